// Round 1
// baseline (665.251 us; speedup 1.0000x reference)
//
#include <hip/hip_runtime.h>
#include <stdint.h>

#define BS 4
#define NN 1024
#define GD 6
#define CIN 256
#define NH 8
#define DH 32
#define HID 16
#define MCS 64

#define PG_ELEMS (BS*NN*NN*GD)                 // 25165824
#define OUT_OFF  PG_ELEMS
#define MASK_OFF (PG_ELEMS + BS*NN*CIN)        // 26214400

__device__ __forceinline__ float swishf(float x) {
    return x * (1.0f / (1.0f + __expf(-x)));
}

// Fused 4096x256 @ 256x256 + bias GEMM; blockIdx.y selects one of up to 3 (W,b,dst).
__global__ __launch_bounds__(256) void gemm3(const float* __restrict__ X,
    const float* __restrict__ W0, const float* __restrict__ B0, float* __restrict__ D0,
    const float* __restrict__ W1, const float* __restrict__ B1, float* __restrict__ D1,
    const float* __restrict__ W2, const float* __restrict__ B2, float* __restrict__ D2)
{
    const float* W; const float* Bv; float* D;
    if (blockIdx.y == 0)      { W = W0; Bv = B0; D = D0; }
    else if (blockIdx.y == 1) { W = W1; Bv = B1; D = D1; }
    else                      { W = W2; Bv = B2; D = D2; }
    const int c  = threadIdx.x;
    const int r0 = blockIdx.x * 16;
    __shared__ float xs[16][CIN];
    #pragma unroll
    for (int r = 0; r < 16; ++r) xs[r][c] = X[(size_t)(r0 + r)*CIN + c];
    __syncthreads();
    float acc[16];
    #pragma unroll
    for (int r = 0; r < 16; ++r) acc[r] = 0.f;
    #pragma unroll 4
    for (int k = 0; k < CIN; ++k) {
        float w = W[(size_t)k*CIN + c];      // coalesced; xs[r][k] broadcasts
        #pragma unroll
        for (int r = 0; r < 16; ++r) acc[r] += xs[r][k] * w;
    }
    float bb = Bv[c];
    #pragma unroll
    for (int r = 0; r < 16; ++r) D[(size_t)(r0 + r)*CIN + c] = acc[r] + bb;
}

// One block per (query i, batch b): pg row copy + dist^2 + bitonic top-64 +
// loc MLP + dot-product feat + softmax + attn*V.
__global__ __launch_bounds__(256) void attn_topk(
    const float* __restrict__ pg, const int* __restrict__ mask,
    const float* __restrict__ lW1g, const float* __restrict__ lb1g,
    const float* __restrict__ lW2g, const float* __restrict__ lb2g,
    const float* __restrict__ lW3g, const float* __restrict__ lb3g,
    const float* __restrict__ Q, const float* __restrict__ Kc, const float* __restrict__ Vc,
    float* __restrict__ O, float* __restrict__ pg_out)
{
    const int i = blockIdx.x, b = blockIdx.y, tid = threadIdx.x;

    __shared__ __align__(16) float g_row[NN*GD];     // 24 KB
    __shared__ unsigned long long keys[NN];          // 8 KB
    __shared__ float q_row[CIN];
    __shared__ float sW1[NH*GD*HID];
    __shared__ float sb1[NH*HID];
    __shared__ float sW2[NH*HID*HID];
    __shared__ float sb2[NH*HID];
    __shared__ float sW3[NH*HID];
    __shared__ float sb3[NH];
    __shared__ float sc[MCS][NH];                    // scores -> attn
    __shared__ int   nj[MCS];
    __shared__ int   nvalid[MCS];

    // ---- stage pg row into LDS and fuse the passthrough copy to d_out ----
    const size_t rowoff = (size_t)(b*NN + i) * (NN*GD);
    const float4* src4 = (const float4*)(pg + rowoff);
    float4* dst4 = (float4*)(pg_out + rowoff);
    float4* g4 = (float4*)g_row;
    for (int t = tid; t < NN*GD/4; t += 256) {
        float4 v = src4[t];
        g4[t] = v;
        dst4[t] = v;
    }
    // ---- stage loc-MLP weights ----
    for (int t = tid; t < NH*GD*HID;  t += 256) sW1[t] = lW1g[t];
    for (int t = tid; t < NH*HID;     t += 256) sb1[t] = lb1g[t];
    for (int t = tid; t < NH*HID*HID; t += 256) sW2[t] = lW2g[t];
    for (int t = tid; t < NH*HID;     t += 256) sb2[t] = lb2g[t];
    if (tid < NH*HID) sW3[tid] = lW3g[tid];
    if (tid < NH)     sb3[tid] = lb3g[tid];
    q_row[tid] = Q[(size_t)(b*NN + i)*CIN + tid];
    __syncthreads();

    // ---- dist^2 keys (masked -> huge); pack (f32bits << 32 | j) ----
    const int* mrow = mask + b*NN;
    for (int j = tid; j < NN; j += 256) {
        float d2 = 0.f;
        #pragma unroll
        for (int g = 0; g < GD; ++g) { float v = g_row[j*GD + g]; d2 += v*v; }
        if (mrow[j] == 0) d2 = 1e30f;
        keys[j] = ((unsigned long long)__float_as_uint(d2) << 32) | (unsigned)j;
    }
    __syncthreads();

    // ---- bitonic sort ascending (1024 u64 keys, 256 threads) ----
    for (unsigned k = 2; k <= NN; k <<= 1) {
        for (unsigned j = k >> 1; j > 0; j >>= 1) {
            for (unsigned idx = tid; idx < NN; idx += 256) {
                unsigned ixj = idx ^ j;
                if (ixj > idx) {
                    unsigned long long a = keys[idx], c2 = keys[ixj];
                    bool up = ((idx & k) == 0);
                    if ((a > c2) == up) { keys[idx] = c2; keys[ixj] = a; }
                }
            }
            __syncthreads();
        }
    }

    // ---- extract 64 nearest ----
    if (tid < MCS) {
        int jm = (int)(keys[tid] & 0xFFFFFFFFu);
        nj[tid] = jm;
        nvalid[tid] = (mrow[jm] != 0);
    }
    __syncthreads();

    // ---- location-kernel MLP: 512 (m,h) pairs, wave-uniform h ----
    #pragma unroll
    for (int pass = 0; pass < 2; ++pass) {
        int p = tid + pass*256;
        int h = p >> 6;        // 0..7, uniform within a wave
        int m = p & 63;
        int jm = nj[m];
        float gv[GD];
        #pragma unroll
        for (int g = 0; g < GD; ++g) gv[g] = g_row[jm*GD + g];
        float h1[HID];
        #pragma unroll
        for (int kk = 0; kk < HID; ++kk) {
            float a = sb1[h*HID + kk];
            #pragma unroll
            for (int g = 0; g < GD; ++g) a += gv[g] * sW1[(h*GD + g)*HID + kk];
            h1[kk] = swishf(a);
        }
        float h2[HID];
        #pragma unroll
        for (int l = 0; l < HID; ++l) {
            float a = sb2[h*HID + l];
            #pragma unroll
            for (int kk = 0; kk < HID; ++kk) a += h1[kk] * sW2[(h*HID + kk)*HID + l];
            h2[l] = swishf(a);
        }
        float a = sb3[h];
        #pragma unroll
        for (int kk = 0; kk < HID; ++kk) a += h2[kk] * sW3[h*HID + kk];
        sc[m][h] = swishf(a);
    }
    __syncthreads();

    // ---- feat: q . k_nbhd via coalesced K-row loads + 32-lane shuffle reduce ----
    {
        const float scale = 0.17677669529663688f;   // 1/sqrt(32)
        const int hh = tid >> 5;
        float qv = q_row[tid];
        for (int m = 0; m < MCS; ++m) {
            int jm = nj[m];
            float kv = Kc[(size_t)(b*NN + jm)*CIN + tid] * qv;
            kv += __shfl_xor(kv, 16);
            kv += __shfl_xor(kv, 8);
            kv += __shfl_xor(kv, 4);
            kv += __shfl_xor(kv, 2);
            kv += __shfl_xor(kv, 1);
            if ((tid & 31) == 0) {
                float s = sc[m][hh] + kv * scale;
                if (!nvalid[m]) s = -1e38f;
                sc[m][hh] = s;
            }
        }
    }
    __syncthreads();

    // ---- softmax over m per head (8 serial threads; tiny) ----
    if (tid < NH) {
        int h = tid;
        float mx = -3.4e38f;
        for (int m = 0; m < MCS; ++m) mx = fmaxf(mx, sc[m][h]);
        float sum = 0.f;
        for (int m = 0; m < MCS; ++m) { float e = __expf(sc[m][h] - mx); sc[m][h] = e; sum += e; }
        float inv = 1.0f / sum;
        for (int m = 0; m < MCS; ++m) sc[m][h] *= inv;
    }
    __syncthreads();

    // ---- out[h,d] = sum_m attn[m,h] * V[jm, h*32+d]; coalesced V rows ----
    {
        const int hh = tid >> 5;
        float acc = 0.f;
        for (int m = 0; m < MCS; ++m) {
            int jm = nj[m];
            acc += sc[m][hh] * Vc[(size_t)(b*NN + jm)*CIN + tid];
        }
        O[(size_t)(b*NN + i)*CIN + tid] = acc;
    }
}

__global__ __launch_bounds__(256) void write_mask(const int* __restrict__ mask, float* __restrict__ dst) {
    int t = blockIdx.x*256 + threadIdx.x;
    if (t < BS*NN) dst[t] = mask[t] ? 1.0f : 0.0f;
}

extern "C" void kernel_launch(void* const* d_in, const int* in_sizes, int n_in,
                              void* d_out, int out_size, void* d_ws, size_t ws_size,
                              hipStream_t stream) {
    const float* pg   = (const float*)d_in[0];
    const float* x    = (const float*)d_in[1];
    const int*   mask = (const int*)d_in[2];
    const float* lW1  = (const float*)d_in[3];
    const float* lb1  = (const float*)d_in[4];
    const float* lW2  = (const float*)d_in[5];
    const float* lb2  = (const float*)d_in[6];
    const float* lW3  = (const float*)d_in[7];
    const float* lb3  = (const float*)d_in[8];
    const float* Wq   = (const float*)d_in[9];
    const float* bq   = (const float*)d_in[10];
    const float* Wk   = (const float*)d_in[11];
    const float* bk   = (const float*)d_in[12];
    const float* Wv   = (const float*)d_in[13];
    const float* bv   = (const float*)d_in[14];
    const float* Wo   = (const float*)d_in[15];
    const float* bo   = (const float*)d_in[16];

    float* out = (float*)d_out;
    float* Q  = (float*)d_ws;
    float* Kc = Q  + (size_t)BS*NN*CIN;
    float* Vc = Kc + (size_t)BS*NN*CIN;
    float* O  = Vc + (size_t)BS*NN*CIN;

    // QKV projections (z = 0,1,2)
    gemm3<<<dim3(BS*NN/16, 3), 256, 0, stream>>>(x, Wq, bq, Q, Wk, bk, Kc, Wv, bv, Vc);
    // top-k + attention (also performs the pairwise_g passthrough copy)
    attn_topk<<<dim3(NN, BS), 256, 0, stream>>>(pg, mask, lW1, lb1, lW2, lb2, lW3, lb3,
                                                Q, Kc, Vc, O, out);
    // output projection
    gemm3<<<dim3(BS*NN/16, 1), 256, 0, stream>>>(O, Wo, bo, out + OUT_OFF,
                                                 Wo, bo, out + OUT_OFF,
                                                 Wo, bo, out + OUT_OFF);
    // mask passthrough (as 0.0/1.0 floats)
    write_mask<<<dim3(16), 256, 0, stream>>>(mask, out + MASK_OFF);
}

// Round 2
// 456.845 us; speedup vs baseline: 1.4562x; 1.4562x over previous
//
#include <hip/hip_runtime.h>
#include <stdint.h>

#define BS 4
#define NN 1024
#define GD 6
#define CIN 256
#define NH 8
#define DH 32
#define HID 16
#define MCS 64

#define PG_ELEMS (BS*NN*NN*GD)                 // 25165824
#define OUT_OFF  PG_ELEMS
#define MASK_OFF (PG_ELEMS + BS*NN*CIN)        // 26214400

__device__ __forceinline__ float swishf(float x) {
    return x * (1.0f / (1.0f + __expf(-x)));
}

// Fused 4096x256 @ 256x256 + bias GEMM; blockIdx.y selects one of up to 3 (W,b,dst).
__global__ __launch_bounds__(256) void gemm3(const float* __restrict__ X,
    const float* __restrict__ W0, const float* __restrict__ B0, float* __restrict__ D0,
    const float* __restrict__ W1, const float* __restrict__ B1, float* __restrict__ D1,
    const float* __restrict__ W2, const float* __restrict__ B2, float* __restrict__ D2)
{
    const float* W; const float* Bv; float* D;
    if (blockIdx.y == 0)      { W = W0; Bv = B0; D = D0; }
    else if (blockIdx.y == 1) { W = W1; Bv = B1; D = D1; }
    else                      { W = W2; Bv = B2; D = D2; }
    const int c  = threadIdx.x;
    const int r0 = blockIdx.x * 16;
    __shared__ float xs[16][CIN];
    #pragma unroll
    for (int r = 0; r < 16; ++r) xs[r][c] = X[(size_t)(r0 + r)*CIN + c];
    __syncthreads();
    float acc[16];
    #pragma unroll
    for (int r = 0; r < 16; ++r) acc[r] = 0.f;
    #pragma unroll 4
    for (int k = 0; k < CIN; ++k) {
        float w = W[(size_t)k*CIN + c];      // coalesced; xs[r][k] broadcasts
        #pragma unroll
        for (int r = 0; r < 16; ++r) acc[r] += xs[r][k] * w;
    }
    float bb = Bv[c];
    #pragma unroll
    for (int r = 0; r < 16; ++r) D[(size_t)(r0 + r)*CIN + c] = acc[r] + bb;
}

// One block per (query i, batch b): pg row copy + dist^2 (keys in registers) +
// 4-level radix select of top-64 + loc MLP + dot-product feat + softmax + attn*V.
__global__ __launch_bounds__(256) void attn_topk(
    const float* __restrict__ pg, const int* __restrict__ mask,
    const float* __restrict__ lW1g, const float* __restrict__ lb1g,
    const float* __restrict__ lW2g, const float* __restrict__ lb2g,
    const float* __restrict__ lW3g, const float* __restrict__ lb3g,
    const float* __restrict__ Q, const float* __restrict__ Kc, const float* __restrict__ Vc,
    float* __restrict__ O, float* __restrict__ pg_out)
{
    const int i = blockIdx.x, b = blockIdx.y, tid = threadIdx.x;

    __shared__ __align__(16) float g_row[NN*GD];     // 24 KB
    // union region: select phase -> hist[256] @0, eqlist[128] @256 ; post-select -> sc[64][8]
    __shared__ __align__(16) unsigned selbuf[512];   // 2 KB
    __shared__ int nj[MCS];                          // bit31 = invalid flag
    __shared__ float sW1[NH*GD*HID];
    __shared__ float sb1[NH*HID];
    __shared__ float sW2[NH*HID*HID];
    __shared__ float sb2[NH*HID];
    __shared__ float sW3[NH*HID];
    __shared__ float sb3[NH];
    __shared__ unsigned wsum[4];
    __shared__ unsigned sel_bin, sel_need, s_cnt, s_eqcnt;

    float (*sc)[NH]   = (float (*)[NH])selbuf;
    unsigned* hist    = selbuf;
    unsigned* eqlist  = selbuf + 256;

    // ---- stage pg row into LDS and fuse the passthrough copy to d_out ----
    const size_t rowoff = (size_t)(b*NN + i) * (NN*GD);
    const float4* src4 = (const float4*)(pg + rowoff);
    float4* dst4 = (float4*)(pg_out + rowoff);
    float4* g4 = (float4*)g_row;
    #pragma unroll
    for (int t = tid; t < NN*GD/4; t += 256) {
        float4 v = src4[t];
        g4[t] = v;
        dst4[t] = v;
    }
    // ---- stage loc-MLP weights ----
    for (int t = tid; t < NH*GD*HID;  t += 256) sW1[t] = lW1g[t];
    for (int t = tid; t < NH*HID;     t += 256) sb1[t] = lb1g[t];
    for (int t = tid; t < NH*HID*HID; t += 256) sW2[t] = lW2g[t];
    for (int t = tid; t < NH*HID;     t += 256) sb2[t] = lb2g[t];
    if (tid < NH*HID) sW3[tid] = lW3g[tid];
    if (tid < NH)     sb3[tid] = lb3g[tid];
    __syncthreads();

    // ---- per-thread dist^2 keys for j = 4*tid .. 4*tid+3 (registers) ----
    const int* mrow = mask + b*NN;
    const int4 mv = ((const int4*)mrow)[tid];
    unsigned key[4];
    {
        const float4* gg = (const float4*)g_row;
        const int base4 = tid * 6;
        {
            float4 a0 = gg[base4 + 0], a1 = gg[base4 + 1], a2 = gg[base4 + 2];
            float d2a = a0.x*a0.x + a0.y*a0.y + a0.z*a0.z + a0.w*a0.w + a1.x*a1.x + a1.y*a1.y;
            float d2b = a1.z*a1.z + a1.w*a1.w + a2.x*a2.x + a2.y*a2.y + a2.z*a2.z + a2.w*a2.w;
            key[0] = __float_as_uint(mv.x ? d2a : 1e30f);
            key[1] = __float_as_uint(mv.y ? d2b : 1e30f);
        }
        {
            float4 a0 = gg[base4 + 3], a1 = gg[base4 + 4], a2 = gg[base4 + 5];
            float d2a = a0.x*a0.x + a0.y*a0.y + a0.z*a0.z + a0.w*a0.w + a1.x*a1.x + a1.y*a1.y;
            float d2b = a1.z*a1.z + a1.w*a1.w + a2.x*a2.x + a2.y*a2.y + a2.z*a2.z + a2.w*a2.w;
            key[2] = __float_as_uint(mv.z ? d2a : 1e30f);
            key[3] = __float_as_uint(mv.w ? d2b : 1e30f);
        }
    }

    // ---- 4-level radix select: find exact 64-smallest threshold ----
    unsigned prefix = 0;
    int need = MCS;
    for (int level = 0; level < 4; ++level) {
        const int shift = 24 - 8*level;
        hist[tid] = 0;
        __syncthreads();
        const unsigned pmask = (level == 0) ? 0u : (0xFFFFFFFFu << (shift + 8));
        #pragma unroll
        for (int r = 0; r < 4; ++r)
            if ((key[r] & pmask) == prefix)
                atomicAdd(&hist[(key[r] >> shift) & 0xFFu], 1u);
        __syncthreads();
        unsigned own = hist[tid];
        unsigned v = own;
        #pragma unroll
        for (int off = 1; off < 64; off <<= 1) {
            unsigned nv = __shfl_up(v, off);
            if ((tid & 63) >= off) v += nv;
        }
        if ((tid & 63) == 63) wsum[tid >> 6] = v;
        __syncthreads();
        unsigned basec = 0;
        for (int w = 0; w < (tid >> 6); ++w) basec += wsum[w];
        unsigned incl = v + basec;
        unsigned excl = incl - own;
        if (excl < (unsigned)need && (unsigned)need <= incl) {
            sel_bin = (unsigned)tid;
            sel_need = (unsigned)need - excl;
        }
        __syncthreads();
        prefix |= (sel_bin << shift);
        need = (int)sel_need;
    }
    const unsigned T = prefix;   // exact 32-bit threshold key; `need` keys equal to T selected
    const int needT = need;

    if (tid == 0) { s_cnt = 0; s_eqcnt = 0; }
    __syncthreads();
    {
        const int vb[4] = { mv.x, mv.y, mv.z, mv.w };
        #pragma unroll
        for (int r = 0; r < 4; ++r) {
            unsigned kk = key[r];
            int j = tid*4 + r;
            if (kk < T) {
                unsigned p = atomicAdd(&s_cnt, 1u);
                nj[p] = j | (vb[r] ? 0 : (int)0x80000000);
            } else if (kk == T) {
                unsigned e = atomicAdd(&s_eqcnt, 1u);
                if (e < 128) eqlist[e] = (unsigned)j;
            }
        }
    }
    __syncthreads();
    if (tid == 0) {
        int ec = (int)s_eqcnt; if (ec > 128) ec = 128;
        int cbase = (int)s_cnt;
        for (int s2 = 0; s2 < needT; ++s2) {
            int bi = -1, bj = 0x7FFFFFFF;
            for (int e = 0; e < ec; ++e) {
                int jj = (int)eqlist[e];
                if (jj < bj) { bj = jj; bi = e; }
            }
            if (bi >= 0) {
                eqlist[bi] = 0x7FFFFFFFu;
                nj[cbase + s2] = bj | (mrow[bj] ? 0 : (int)0x80000000);
            }
        }
    }
    __syncthreads();   // nj ready; selbuf now reusable as sc[][]

    // ---- location-kernel MLP: 512 (m,h) pairs, wave-uniform h ----
    #pragma unroll
    for (int pass = 0; pass < 2; ++pass) {
        int p = tid + pass*256;
        int h = p >> 6;        // 0..7, uniform within a wave
        int m = p & 63;
        int jm = nj[m] & 0x7FFFFFFF;
        float gv[GD];
        #pragma unroll
        for (int g = 0; g < GD; ++g) gv[g] = g_row[jm*GD + g];
        float h1[HID];
        #pragma unroll
        for (int kk = 0; kk < HID; ++kk) {
            float a = sb1[h*HID + kk];
            #pragma unroll
            for (int g = 0; g < GD; ++g) a += gv[g] * sW1[(h*GD + g)*HID + kk];
            h1[kk] = swishf(a);
        }
        float h2[HID];
        #pragma unroll
        for (int l = 0; l < HID; ++l) {
            float a = sb2[h*HID + l];
            #pragma unroll
            for (int kk = 0; kk < HID; ++kk) a += h1[kk] * sW2[(h*HID + kk)*HID + l];
            h2[l] = swishf(a);
        }
        float a = sb3[h];
        #pragma unroll
        for (int kk = 0; kk < HID; ++kk) a += h2[kk] * sW3[h*HID + kk];
        sc[m][h] = swishf(a);
    }
    __syncthreads();

    // ---- feat: q . k_nbhd via coalesced K-row loads + 32-lane shuffle reduce ----
    {
        const float scale = 0.17677669529663688f;   // 1/sqrt(32)
        const int hh = tid >> 5;
        float qv = Q[(size_t)(b*NN + i)*CIN + tid];
        for (int m = 0; m < MCS; ++m) {
            int code = nj[m];
            int jm = code & 0x7FFFFFFF;
            float kv = Kc[(size_t)(b*NN + jm)*CIN + tid] * qv;
            kv += __shfl_xor(kv, 16);
            kv += __shfl_xor(kv, 8);
            kv += __shfl_xor(kv, 4);
            kv += __shfl_xor(kv, 2);
            kv += __shfl_xor(kv, 1);
            if ((tid & 31) == 0) {
                float s = sc[m][hh] + kv * scale;
                if (code < 0) s = -1e38f;
                sc[m][hh] = s;
            }
        }
    }
    __syncthreads();

    // ---- softmax over m per head (8 serial threads; tiny) ----
    if (tid < NH) {
        int h = tid;
        float mx = -3.4e38f;
        for (int m = 0; m < MCS; ++m) mx = fmaxf(mx, sc[m][h]);
        float sum = 0.f;
        for (int m = 0; m < MCS; ++m) { float e = __expf(sc[m][h] - mx); sc[m][h] = e; sum += e; }
        float inv = 1.0f / sum;
        for (int m = 0; m < MCS; ++m) sc[m][h] *= inv;
    }
    __syncthreads();

    // ---- out[h,d] = sum_m attn[m,h] * V[jm, h*32+d]; coalesced V rows ----
    {
        const int hh = tid >> 5;
        float acc = 0.f;
        for (int m = 0; m < MCS; ++m) {
            int jm = nj[m] & 0x7FFFFFFF;
            acc += sc[m][hh] * Vc[(size_t)(b*NN + jm)*CIN + tid];
        }
        O[(size_t)(b*NN + i)*CIN + tid] = acc;
    }
}

__global__ __launch_bounds__(256) void write_mask(const int* __restrict__ mask, float* __restrict__ dst) {
    int t = blockIdx.x*256 + threadIdx.x;
    if (t < BS*NN) dst[t] = mask[t] ? 1.0f : 0.0f;
}

extern "C" void kernel_launch(void* const* d_in, const int* in_sizes, int n_in,
                              void* d_out, int out_size, void* d_ws, size_t ws_size,
                              hipStream_t stream) {
    const float* pg   = (const float*)d_in[0];
    const float* x    = (const float*)d_in[1];
    const int*   mask = (const int*)d_in[2];
    const float* lW1  = (const float*)d_in[3];
    const float* lb1  = (const float*)d_in[4];
    const float* lW2  = (const float*)d_in[5];
    const float* lb2  = (const float*)d_in[6];
    const float* lW3  = (const float*)d_in[7];
    const float* lb3  = (const float*)d_in[8];
    const float* Wq   = (const float*)d_in[9];
    const float* bq   = (const float*)d_in[10];
    const float* Wk   = (const float*)d_in[11];
    const float* bk   = (const float*)d_in[12];
    const float* Wv   = (const float*)d_in[13];
    const float* bv   = (const float*)d_in[14];
    const float* Wo   = (const float*)d_in[15];
    const float* bo   = (const float*)d_in[16];

    float* out = (float*)d_out;
    float* Q  = (float*)d_ws;
    float* Kc = Q  + (size_t)BS*NN*CIN;
    float* Vc = Kc + (size_t)BS*NN*CIN;
    float* O  = Vc + (size_t)BS*NN*CIN;

    // QKV projections (z = 0,1,2)
    gemm3<<<dim3(BS*NN/16, 3), 256, 0, stream>>>(x, Wq, bq, Q, Wk, bk, Kc, Wv, bv, Vc);
    // top-k + attention (also performs the pairwise_g passthrough copy)
    attn_topk<<<dim3(NN, BS), 256, 0, stream>>>(pg, mask, lW1, lb1, lW2, lb2, lW3, lb3,
                                                Q, Kc, Vc, O, out);
    // output projection
    gemm3<<<dim3(BS*NN/16, 1), 256, 0, stream>>>(O, Wo, bo, out + OUT_OFF,
                                                 Wo, bo, out + OUT_OFF,
                                                 Wo, bo, out + OUT_OFF);
    // mask passthrough (as 0.0/1.0 floats)
    write_mask<<<dim3(16), 256, 0, stream>>>(mask, out + MASK_OFF);
}

// Round 3
// 420.722 us; speedup vs baseline: 1.5812x; 1.0859x over previous
//
#include <hip/hip_runtime.h>
#include <stdint.h>

#define BS 4
#define NN 1024
#define GD 6
#define CIN 256
#define NH 8
#define DH 32
#define HID 16
#define MCS 64

#define PG_ELEMS (BS*NN*NN*GD)                 // 25165824
#define OUT_OFF  PG_ELEMS
#define MASK_OFF (PG_ELEMS + BS*NN*CIN)        // 26214400

__device__ __forceinline__ float swishf(float x) {
    return x * (1.0f / (1.0f + __expf(-x)));
}

// Fused 4096x256 @ 256x256 + bias GEMM; blockIdx.y selects one of up to 3 (W,b,dst).
__global__ __launch_bounds__(256) void gemm3(const float* __restrict__ X,
    const float* __restrict__ W0, const float* __restrict__ B0, float* __restrict__ D0,
    const float* __restrict__ W1, const float* __restrict__ B1, float* __restrict__ D1,
    const float* __restrict__ W2, const float* __restrict__ B2, float* __restrict__ D2)
{
    const float* W; const float* Bv; float* D;
    if (blockIdx.y == 0)      { W = W0; Bv = B0; D = D0; }
    else if (blockIdx.y == 1) { W = W1; Bv = B1; D = D1; }
    else                      { W = W2; Bv = B2; D = D2; }
    const int c  = threadIdx.x;
    const int r0 = blockIdx.x * 16;
    __shared__ float xs[16][CIN];
    #pragma unroll
    for (int r = 0; r < 16; ++r) xs[r][c] = X[(size_t)(r0 + r)*CIN + c];
    __syncthreads();
    float acc[16];
    #pragma unroll
    for (int r = 0; r < 16; ++r) acc[r] = 0.f;
    #pragma unroll 4
    for (int k = 0; k < CIN; ++k) {
        float w = W[(size_t)k*CIN + c];      // coalesced; xs[r][k] broadcasts
        #pragma unroll
        for (int r = 0; r < 16; ++r) acc[r] += xs[r][k] * w;
    }
    float bb = Bv[c];
    #pragma unroll
    for (int r = 0; r < 16; ++r) D[(size_t)(r0 + r)*CIN + c] = acc[r] + bb;
}

// One block per (query i, batch b). LDS kept under 160K/6 so 6 blocks/CU fit.
__global__ __launch_bounds__(256) void attn_topk(
    const float* __restrict__ pg, const int* __restrict__ mask,
    const float* __restrict__ lW1g, const float* __restrict__ lb1g,
    const float* __restrict__ lW2g, const float* __restrict__ lb2g,
    const float* __restrict__ lW3g, const float* __restrict__ lb3g,
    const float* __restrict__ Q, const float* __restrict__ Kc, const float* __restrict__ Vc,
    float* __restrict__ O, float* __restrict__ pg_out)
{
    const int i = blockIdx.x, b = blockIdx.y, tid = threadIdx.x;
    const int lane = tid & 63;

    __shared__ __align__(16) float g_row[NN*GD];     // 24 KB
    // union: select phase -> hist[256] u32 @0, eqlist[64] u32 @256 ; later -> sc[64][8] f32
    __shared__ __align__(16) unsigned selbuf[512];   // 2 KB
    __shared__ int nj[MCS];                          // bit31 = invalid flag
    __shared__ unsigned wsum[4];
    __shared__ unsigned sel_bin, sel_need, s_cnt, s_eqcnt;

    float (*sc)[NH]   = (float (*)[NH])selbuf;
    unsigned* hist    = selbuf;
    unsigned* eqlist  = selbuf + 256;

    // ---- stage pg row into LDS and fuse the passthrough copy to d_out ----
    const size_t rowoff = (size_t)(b*NN + i) * (NN*GD);
    const float4* src4 = (const float4*)(pg + rowoff);
    float4* dst4 = (float4*)(pg_out + rowoff);
    float4* g4 = (float4*)g_row;
    #pragma unroll
    for (int t = tid; t < NN*GD/4; t += 256) {
        float4 v = src4[t];
        g4[t] = v;
        dst4[t] = v;
    }
    float qv = Q[(size_t)(b*NN + i)*CIN + tid];      // prefetch for feat phase
    __syncthreads();

    // ---- per-thread dist^2 keys for j = 4*tid .. 4*tid+3 (registers) ----
    const int* mrow = mask + b*NN;
    const int4 mv = ((const int4*)mrow)[tid];
    unsigned key[4];
    {
        const float4* gg = (const float4*)g_row;
        const int base4 = tid * 6;
        {
            float4 a0 = gg[base4 + 0], a1 = gg[base4 + 1], a2 = gg[base4 + 2];
            float d2a = a0.x*a0.x + a0.y*a0.y + a0.z*a0.z + a0.w*a0.w + a1.x*a1.x + a1.y*a1.y;
            float d2b = a1.z*a1.z + a1.w*a1.w + a2.x*a2.x + a2.y*a2.y + a2.z*a2.z + a2.w*a2.w;
            key[0] = __float_as_uint(mv.x ? d2a : 1e30f);
            key[1] = __float_as_uint(mv.y ? d2b : 1e30f);
        }
        {
            float4 a0 = gg[base4 + 3], a1 = gg[base4 + 4], a2 = gg[base4 + 5];
            float d2a = a0.x*a0.x + a0.y*a0.y + a0.z*a0.z + a0.w*a0.w + a1.x*a1.x + a1.y*a1.y;
            float d2b = a1.z*a1.z + a1.w*a1.w + a2.x*a2.x + a2.y*a2.y + a2.z*a2.z + a2.w*a2.w;
            key[2] = __float_as_uint(mv.z ? d2a : 1e30f);
            key[3] = __float_as_uint(mv.w ? d2b : 1e30f);
        }
    }

    // ---- 4-level radix select: find exact 64-smallest threshold ----
    unsigned prefix = 0;
    int need = MCS;
    for (int level = 0; level < 4; ++level) {
        const int shift = 24 - 8*level;
        hist[tid] = 0;
        __syncthreads();
        if (level == 0) {
            // digits cluster into ~5 bins (float exponents of chi^2(6) d^2):
            // ballot-clustered counting, one atomic per distinct digit per wave.
            #pragma unroll
            for (int r = 0; r < 4; ++r) {
                unsigned d = key[r] >> 24;
                unsigned long long todo = __ballot(true);
                while (todo) {
                    int leader = (int)(__ffsll((unsigned long long)todo) - 1);
                    unsigned dl = __shfl(d, leader);
                    unsigned long long match = __ballot(d == dl);
                    if (lane == leader) atomicAdd(&hist[dl], (unsigned)__popcll(match));
                    todo &= ~match;
                }
            }
        } else {
            const unsigned pmask = 0xFFFFFFFFu << (shift + 8);
            #pragma unroll
            for (int r = 0; r < 4; ++r)
                if ((key[r] & pmask) == prefix)
                    atomicAdd(&hist[(key[r] >> shift) & 0xFFu], 1u);
        }
        __syncthreads();
        unsigned own = hist[tid];
        unsigned v = own;
        #pragma unroll
        for (int off = 1; off < 64; off <<= 1) {
            unsigned nv = __shfl_up(v, off);
            if (lane >= off) v += nv;
        }
        if (lane == 63) wsum[tid >> 6] = v;
        __syncthreads();
        unsigned basec = 0;
        for (int w = 0; w < (tid >> 6); ++w) basec += wsum[w];
        unsigned incl = v + basec;
        unsigned excl = incl - own;
        if (excl < (unsigned)need && (unsigned)need <= incl) {
            sel_bin = (unsigned)tid;
            sel_need = (unsigned)need - excl;
        }
        __syncthreads();
        prefix |= (sel_bin << shift);
        need = (int)sel_need;
    }
    const unsigned T = prefix;   // exact threshold key; `need` keys equal to T selected
    const int needT = need;

    if (tid == 0) { s_cnt = 0; s_eqcnt = 0; }
    __syncthreads();
    {
        const int vb[4] = { mv.x, mv.y, mv.z, mv.w };
        #pragma unroll
        for (int r = 0; r < 4; ++r) {
            unsigned kk = key[r];
            int j = tid*4 + r;
            if (kk < T) {
                unsigned p = atomicAdd(&s_cnt, 1u);
                nj[p] = j | (vb[r] ? 0 : (int)0x80000000);
            } else if (kk == T) {
                unsigned e = atomicAdd(&s_eqcnt, 1u);
                if (e < 64) eqlist[e] = (unsigned)j;
            }
        }
    }
    __syncthreads();
    if (tid == 0) {
        int ec = (int)s_eqcnt; if (ec > 64) ec = 64;
        int cbase = (int)s_cnt;
        for (int s2 = 0; s2 < needT; ++s2) {
            int bi = -1, bj = 0x7FFFFFFF;
            for (int e = 0; e < ec; ++e) {
                int jj = (int)eqlist[e];
                if (jj < bj) { bj = jj; bi = e; }
            }
            if (bi >= 0) {
                eqlist[bi] = 0x7FFFFFFFu;
                nj[cbase + s2] = bj | (mrow[bj] ? 0 : (int)0x80000000);
            }
        }
    }
    __syncthreads();   // nj ready; selbuf now reusable as sc[][]

    // ---- location-kernel MLP: wave-uniform head -> scalar (s_load) weights ----
    #pragma unroll
    for (int pass = 0; pass < 2; ++pass) {
        const int h = __builtin_amdgcn_readfirstlane((tid >> 6) + pass*4);   // 0..7
        const int m = lane;
        const int jm = nj[m] & 0x7FFFFFFF;
        const float* W1h = lW1g + h*(GD*HID);
        const float* B1h = lb1g + h*HID;
        const float* W2h = lW2g + h*(HID*HID);
        const float* B2h = lb2g + h*HID;
        const float* W3h = lW3g + h*HID;
        float gv[GD];
        #pragma unroll
        for (int g = 0; g < GD; ++g) gv[g] = g_row[jm*GD + g];
        float h1[HID];
        #pragma unroll
        for (int kk = 0; kk < HID; ++kk) {
            float a = B1h[kk];
            #pragma unroll
            for (int g = 0; g < GD; ++g) a += gv[g] * W1h[g*HID + kk];
            h1[kk] = swishf(a);
        }
        float h2[HID];
        #pragma unroll
        for (int l = 0; l < HID; ++l) {
            float a = B2h[l];
            #pragma unroll
            for (int kk = 0; kk < HID; ++kk) a += h1[kk] * W2h[kk*HID + l];
            h2[l] = swishf(a);
        }
        float a3 = lb3g[h];
        #pragma unroll
        for (int kk = 0; kk < HID; ++kk) a3 += h2[kk] * W3h[kk];
        sc[m][h] = swishf(a3);
    }
    __syncthreads();

    // ---- feat: q . k_nbhd via coalesced K-row loads + 32-lane shuffle reduce ----
    {
        const float scale = 0.17677669529663688f;   // 1/sqrt(32)
        const int hh = tid >> 5;
        #pragma unroll 4
        for (int m = 0; m < MCS; ++m) {
            int code = nj[m];
            int jm = code & 0x7FFFFFFF;
            float kv = Kc[(size_t)(b*NN + jm)*CIN + tid] * qv;
            kv += __shfl_xor(kv, 16);
            kv += __shfl_xor(kv, 8);
            kv += __shfl_xor(kv, 4);
            kv += __shfl_xor(kv, 2);
            kv += __shfl_xor(kv, 1);
            if ((tid & 31) == 0) {
                float s = sc[m][hh] + kv * scale;
                if (code < 0) s = -1e38f;
                sc[m][hh] = s;
            }
        }
    }
    __syncthreads();

    // ---- softmax over m, wave-parallel: lane = m, wave (x2 passes) = head ----
    #pragma unroll
    for (int pass = 0; pass < 2; ++pass) {
        int h = (tid >> 6) + pass*4;
        float s = sc[lane][h];
        float mx = s;
        #pragma unroll
        for (int off = 32; off; off >>= 1) mx = fmaxf(mx, __shfl_xor(mx, off));
        float e = __expf(s - mx);
        float sum = e;
        #pragma unroll
        for (int off = 32; off; off >>= 1) sum += __shfl_xor(sum, off);
        sc[lane][h] = e / sum;
    }
    __syncthreads();

    // ---- out[h,d] = sum_m attn[m,h] * V[jm, h*32+d]; coalesced V rows ----
    {
        const int hh = tid >> 5;
        float acc = 0.f;
        #pragma unroll 8
        for (int m = 0; m < MCS; ++m) {
            int jm = nj[m] & 0x7FFFFFFF;
            acc += sc[m][hh] * Vc[(size_t)(b*NN + jm)*CIN + tid];
        }
        O[(size_t)(b*NN + i)*CIN + tid] = acc;
    }
}

__global__ __launch_bounds__(256) void write_mask(const int* __restrict__ mask, float* __restrict__ dst) {
    int t = blockIdx.x*256 + threadIdx.x;
    if (t < BS*NN) dst[t] = mask[t] ? 1.0f : 0.0f;
}

extern "C" void kernel_launch(void* const* d_in, const int* in_sizes, int n_in,
                              void* d_out, int out_size, void* d_ws, size_t ws_size,
                              hipStream_t stream) {
    const float* pg   = (const float*)d_in[0];
    const float* x    = (const float*)d_in[1];
    const int*   mask = (const int*)d_in[2];
    const float* lW1  = (const float*)d_in[3];
    const float* lb1  = (const float*)d_in[4];
    const float* lW2  = (const float*)d_in[5];
    const float* lb2  = (const float*)d_in[6];
    const float* lW3  = (const float*)d_in[7];
    const float* lb3  = (const float*)d_in[8];
    const float* Wq   = (const float*)d_in[9];
    const float* bq   = (const float*)d_in[10];
    const float* Wk   = (const float*)d_in[11];
    const float* bk   = (const float*)d_in[12];
    const float* Wv   = (const float*)d_in[13];
    const float* bv   = (const float*)d_in[14];
    const float* Wo   = (const float*)d_in[15];
    const float* bo   = (const float*)d_in[16];

    float* out = (float*)d_out;
    float* Q  = (float*)d_ws;
    float* Kc = Q  + (size_t)BS*NN*CIN;
    float* Vc = Kc + (size_t)BS*NN*CIN;
    float* O  = Vc + (size_t)BS*NN*CIN;

    // QKV projections (z = 0,1,2)
    gemm3<<<dim3(BS*NN/16, 3), 256, 0, stream>>>(x, Wq, bq, Q, Wk, bk, Kc, Wv, bv, Vc);
    // top-k + attention (also performs the pairwise_g passthrough copy)
    attn_topk<<<dim3(NN, BS), 256, 0, stream>>>(pg, mask, lW1, lb1, lW2, lb2, lW3, lb3,
                                                Q, Kc, Vc, O, out);
    // output projection
    gemm3<<<dim3(BS*NN/16, 1), 256, 0, stream>>>(O, Wo, bo, out + OUT_OFF,
                                                 Wo, bo, out + OUT_OFF,
                                                 Wo, bo, out + OUT_OFF);
    // mask passthrough (as 0.0/1.0 floats)
    write_mask<<<dim3(16), 256, 0, stream>>>(mask, out + MASK_OFF);
}

// Round 5
// 385.114 us; speedup vs baseline: 1.7274x; 1.0925x over previous
//
#include <hip/hip_runtime.h>
#include <stdint.h>

#define BS 4
#define NN 1024
#define GD 6
#define CIN 256
#define NH 8
#define DH 32
#define HID 16
#define MCS 64

#define PG_ELEMS (BS*NN*NN*GD)                 // 25165824
#define OUT_OFF  PG_ELEMS
#define MASK_OFF (PG_ELEMS + BS*NN*CIN)        // 26214400

typedef float vfloat4 __attribute__((ext_vector_type(4)));   // native clang vector (nontemporal-ok)

__device__ __forceinline__ float swishf(float x) {
    return x * (1.0f / (1.0f + __expf(-x)));
}

// Fused 4096x256 @ 256x256 + bias GEMM; blockIdx.y selects one of up to 3 (W,b,dst).
__global__ __launch_bounds__(256) void gemm3(const float* __restrict__ X,
    const float* __restrict__ W0, const float* __restrict__ B0, float* __restrict__ D0,
    const float* __restrict__ W1, const float* __restrict__ B1, float* __restrict__ D1,
    const float* __restrict__ W2, const float* __restrict__ B2, float* __restrict__ D2)
{
    const float* W; const float* Bv; float* D;
    if (blockIdx.y == 0)      { W = W0; Bv = B0; D = D0; }
    else if (blockIdx.y == 1) { W = W1; Bv = B1; D = D1; }
    else                      { W = W2; Bv = B2; D = D2; }
    const int c  = threadIdx.x;
    const int r0 = blockIdx.x * 16;
    __shared__ float xs[16][CIN];
    #pragma unroll
    for (int r = 0; r < 16; ++r) xs[r][c] = X[(size_t)(r0 + r)*CIN + c];
    __syncthreads();
    float acc[16];
    #pragma unroll
    for (int r = 0; r < 16; ++r) acc[r] = 0.f;
    #pragma unroll 4
    for (int k = 0; k < CIN; ++k) {
        float w = W[(size_t)k*CIN + c];      // coalesced; xs[r][k] broadcasts
        #pragma unroll
        for (int r = 0; r < 16; ++r) acc[r] += xs[r][k] * w;
    }
    float bb = Bv[c];
    #pragma unroll
    for (int r = 0; r < 16; ++r) D[(size_t)(r0 + r)*CIN + c] = acc[r] + bb;
}

// One block per (query i, batch b). No g_row staging: dist^2 from registers,
// only the 64 selected rows land in LDS (compact, stride-7 padded).
__global__ __launch_bounds__(256, 7) void attn_topk(
    const float* __restrict__ pg, const int* __restrict__ mask,
    const float* __restrict__ lW1g, const float* __restrict__ lb1g,
    const float* __restrict__ lW2g, const float* __restrict__ lb2g,
    const float* __restrict__ lW3g, const float* __restrict__ lb3g,
    const float* __restrict__ Q, const float* __restrict__ Kc, const float* __restrict__ Vc,
    float* __restrict__ O, float* __restrict__ pg_out)
{
    const int i = blockIdx.x, b = blockIdx.y, tid = threadIdx.x;
    const int lane = tid & 63;

    // union: select phase -> hist[256] u32 @0, eqlist[64] u32 @256 ; later -> sc[64][8] f32
    __shared__ __align__(16) unsigned selbuf[512];   // 2 KB
    __shared__ float sg[MCS*7];                      // compact nbhd_g, stride 7 (1.75 KB)
    __shared__ int nj[MCS];                          // bit31 = invalid flag
    __shared__ unsigned wsum[4];
    __shared__ unsigned sel_bin, sel_need, s_cnt, s_eqcnt;

    float (*sc)[NH]   = (float (*)[NH])selbuf;
    unsigned* hist    = selbuf;
    unsigned* eqlist  = selbuf + 256;

    // ---- coalesced passthrough copy (nontemporal stores; pg_out never re-read) ----
    const size_t rowoff = (size_t)(b*NN + i) * (NN*GD);
    const vfloat4* src4 = (const vfloat4*)(pg + rowoff);
    vfloat4* dst4 = (vfloat4*)(pg_out + rowoff);
    #pragma unroll
    for (int t = 0; t < 6; ++t) {
        vfloat4 v = src4[tid + 256*t];
        __builtin_nontemporal_store(v, &dst4[tid + 256*t]);
    }
    float qv = Q[(size_t)(b*NN + i)*CIN + tid];      // prefetch for feat phase

    // ---- per-thread rows j=4t..4t+3: 6 consecutive float4 (L2-warm), dist^2 in regs ----
    const int* mrow = mask + b*NN;
    const int4 mv = ((const int4*)mrow)[tid];
    const vfloat4* gg = src4 + tid*6;
    vfloat4 a0 = gg[0], a1 = gg[1], a2 = gg[2], a3 = gg[3], a4 = gg[4], a5 = gg[5];
    float rv[4][6];
    rv[0][0]=a0.x; rv[0][1]=a0.y; rv[0][2]=a0.z; rv[0][3]=a0.w; rv[0][4]=a1.x; rv[0][5]=a1.y;
    rv[1][0]=a1.z; rv[1][1]=a1.w; rv[1][2]=a2.x; rv[1][3]=a2.y; rv[1][4]=a2.z; rv[1][5]=a2.w;
    rv[2][0]=a3.x; rv[2][1]=a3.y; rv[2][2]=a3.z; rv[2][3]=a3.w; rv[2][4]=a4.x; rv[2][5]=a4.y;
    rv[3][0]=a4.z; rv[3][1]=a4.w; rv[3][2]=a5.x; rv[3][3]=a5.y; rv[3][4]=a5.z; rv[3][5]=a5.w;
    const int vb[4] = { mv.x, mv.y, mv.z, mv.w };
    unsigned key[4];
    #pragma unroll
    for (int r = 0; r < 4; ++r) {
        float d2 = rv[r][0]*rv[r][0] + rv[r][1]*rv[r][1] + rv[r][2]*rv[r][2]
                 + rv[r][3]*rv[r][3] + rv[r][4]*rv[r][4] + rv[r][5]*rv[r][5];
        key[r] = __float_as_uint(vb[r] ? d2 : 1e30f);
    }

    // ---- 4-level radix select: find exact 64-smallest threshold ----
    unsigned prefix = 0;
    int need = MCS;
    for (int level = 0; level < 4; ++level) {
        const int shift = 24 - 8*level;
        hist[tid] = 0;
        __syncthreads();
        if (level == 0) {
            // digits cluster into ~5 bins: ballot-clustered counting,
            // one atomic per distinct digit per wave.
            #pragma unroll
            for (int r = 0; r < 4; ++r) {
                unsigned d = key[r] >> 24;
                unsigned long long todo = __ballot(true);
                while (todo) {
                    int leader = (int)(__ffsll((unsigned long long)todo) - 1);
                    unsigned dl = __shfl(d, leader);
                    unsigned long long match = __ballot(d == dl);
                    if (lane == leader) atomicAdd(&hist[dl], (unsigned)__popcll(match));
                    todo &= ~match;
                }
            }
        } else {
            const unsigned pmask = 0xFFFFFFFFu << (shift + 8);
            #pragma unroll
            for (int r = 0; r < 4; ++r)
                if ((key[r] & pmask) == prefix)
                    atomicAdd(&hist[(key[r] >> shift) & 0xFFu], 1u);
        }
        __syncthreads();
        unsigned own = hist[tid];
        unsigned v = own;
        #pragma unroll
        for (int off = 1; off < 64; off <<= 1) {
            unsigned nv = __shfl_up(v, off);
            if (lane >= off) v += nv;
        }
        if (lane == 63) wsum[tid >> 6] = v;
        __syncthreads();
        unsigned basec = 0;
        for (int w = 0; w < (tid >> 6); ++w) basec += wsum[w];
        unsigned incl = v + basec;
        unsigned excl = incl - own;
        if (excl < (unsigned)need && (unsigned)need <= incl) {
            sel_bin = (unsigned)tid;
            sel_need = (unsigned)need - excl;
        }
        __syncthreads();
        prefix |= (sel_bin << shift);
        need = (int)sel_need;
    }
    const unsigned T = prefix;   // exact threshold key; `need` keys equal to T selected
    const int needT = need;

    if (tid == 0) { s_cnt = 0; s_eqcnt = 0; }
    __syncthreads();
    // ---- compaction: owners scatter their selected rows straight into LDS ----
    #pragma unroll
    for (int r = 0; r < 4; ++r) {
        unsigned kk = key[r];
        int j = tid*4 + r;
        if (kk < T) {
            unsigned p = atomicAdd(&s_cnt, 1u);
            nj[p] = j | (vb[r] ? 0 : (int)0x80000000);
            #pragma unroll
            for (int g = 0; g < GD; ++g) sg[p*7 + g] = rv[r][g];
        } else if (kk == T) {
            unsigned e = atomicAdd(&s_eqcnt, 1u);
            if (e < 64) eqlist[e] = (unsigned)j;
        }
    }
    __syncthreads();
    const int cbase = (int)s_cnt;
    if (tid == 0) {
        int ec = (int)s_eqcnt; if (ec > 64) ec = 64;
        for (int s2 = 0; s2 < needT; ++s2) {
            int bi = -1, bj = 0x7FFFFFFF;
            for (int e = 0; e < ec; ++e) {
                int jj = (int)eqlist[e];
                if (jj < bj) { bj = jj; bi = e; }
            }
            if (bi >= 0) {
                eqlist[bi] = 0x7FFFFFFFu;
                nj[cbase + s2] = bj | (mrow[bj] ? 0 : (int)0x80000000);
            }
        }
    }
    __syncthreads();
    // owners of tie keys fill the g-values for the tie slots (needT is tiny)
    #pragma unroll
    for (int r = 0; r < 4; ++r) {
        if (key[r] == T) {
            int j = tid*4 + r;
            for (int s2 = 0; s2 < needT; ++s2)
                if ((nj[cbase + s2] & 0x7FFFFFFF) == j) {
                    #pragma unroll
                    for (int g = 0; g < GD; ++g) sg[(cbase + s2)*7 + g] = rv[r][g];
                }
        }
    }
    __syncthreads();   // nj+sg ready; selbuf now reusable as sc[][]

    // ---- location-kernel MLP: wave-uniform head -> scalar (s_load) weights ----
    #pragma unroll
    for (int pass = 0; pass < 2; ++pass) {
        const int h = __builtin_amdgcn_readfirstlane((tid >> 6) + pass*4);   // 0..7
        const int m = lane;
        const float* W1h = lW1g + h*(GD*HID);
        const float* B1h = lb1g + h*HID;
        const float* W2h = lW2g + h*(HID*HID);
        const float* B2h = lb2g + h*HID;
        const float* W3h = lW3g + h*HID;
        float gv[GD];
        #pragma unroll
        for (int g = 0; g < GD; ++g) gv[g] = sg[m*7 + g];
        float h1[HID];
        #pragma unroll
        for (int kk = 0; kk < HID; ++kk) {
            float a = B1h[kk];
            #pragma unroll
            for (int g = 0; g < GD; ++g) a += gv[g] * W1h[g*HID + kk];
            h1[kk] = swishf(a);
        }
        float h2[HID];
        #pragma unroll
        for (int l = 0; l < HID; ++l) {
            float a = B2h[l];
            #pragma unroll
            for (int kk = 0; kk < HID; ++kk) a += h1[kk] * W2h[kk*HID + l];
            h2[l] = swishf(a);
        }
        float a3 = lb3g[h];
        #pragma unroll
        for (int kk = 0; kk < HID; ++kk) a3 += h2[kk] * W3h[kk];
        sc[m][h] = swishf(a3);
    }
    __syncthreads();

    // ---- feat: q . k_nbhd via coalesced K-row loads + 32-lane shuffle reduce ----
    {
        const float scale = 0.17677669529663688f;   // 1/sqrt(32)
        const int hh = tid >> 5;
        #pragma unroll 4
        for (int m = 0; m < MCS; ++m) {
            int code = nj[m];
            int jm = code & 0x7FFFFFFF;
            float kv = Kc[(size_t)(b*NN + jm)*CIN + tid] * qv;
            kv += __shfl_xor(kv, 16);
            kv += __shfl_xor(kv, 8);
            kv += __shfl_xor(kv, 4);
            kv += __shfl_xor(kv, 2);
            kv += __shfl_xor(kv, 1);
            if ((tid & 31) == 0) {
                float s = sc[m][hh] + kv * scale;
                if (code < 0) s = -1e38f;
                sc[m][hh] = s;
            }
        }
    }
    __syncthreads();

    // ---- softmax over m, wave-parallel: lane = m, wave (x2 passes) = head ----
    #pragma unroll
    for (int pass = 0; pass < 2; ++pass) {
        int h = (tid >> 6) + pass*4;
        float s = sc[lane][h];
        float mx = s;
        #pragma unroll
        for (int off = 32; off; off >>= 1) mx = fmaxf(mx, __shfl_xor(mx, off));
        float e = __expf(s - mx);
        float sum = e;
        #pragma unroll
        for (int off = 32; off; off >>= 1) sum += __shfl_xor(sum, off);
        sc[lane][h] = e / sum;
    }
    __syncthreads();

    // ---- out[h,d] = sum_m attn[m,h] * V[jm, h*32+d]; coalesced V rows ----
    {
        const int hh = tid >> 5;
        float acc = 0.f;
        #pragma unroll 8
        for (int m = 0; m < MCS; ++m) {
            int jm = nj[m] & 0x7FFFFFFF;
            acc += sc[m][hh] * Vc[(size_t)(b*NN + jm)*CIN + tid];
        }
        O[(size_t)(b*NN + i)*CIN + tid] = acc;
    }
}

__global__ __launch_bounds__(256) void write_mask(const int* __restrict__ mask, float* __restrict__ dst) {
    int t = blockIdx.x*256 + threadIdx.x;
    if (t < BS*NN) dst[t] = mask[t] ? 1.0f : 0.0f;
}

extern "C" void kernel_launch(void* const* d_in, const int* in_sizes, int n_in,
                              void* d_out, int out_size, void* d_ws, size_t ws_size,
                              hipStream_t stream) {
    const float* pg   = (const float*)d_in[0];
    const float* x    = (const float*)d_in[1];
    const int*   mask = (const int*)d_in[2];
    const float* lW1  = (const float*)d_in[3];
    const float* lb1  = (const float*)d_in[4];
    const float* lW2  = (const float*)d_in[5];
    const float* lb2  = (const float*)d_in[6];
    const float* lW3  = (const float*)d_in[7];
    const float* lb3  = (const float*)d_in[8];
    const float* Wq   = (const float*)d_in[9];
    const float* bq   = (const float*)d_in[10];
    const float* Wk   = (const float*)d_in[11];
    const float* bk   = (const float*)d_in[12];
    const float* Wv   = (const float*)d_in[13];
    const float* bv   = (const float*)d_in[14];
    const float* Wo   = (const float*)d_in[15];
    const float* bo   = (const float*)d_in[16];

    float* out = (float*)d_out;
    float* Q  = (float*)d_ws;
    float* Kc = Q  + (size_t)BS*NN*CIN;
    float* Vc = Kc + (size_t)BS*NN*CIN;
    float* O  = Vc + (size_t)BS*NN*CIN;

    // QKV projections (z = 0,1,2)
    gemm3<<<dim3(BS*NN/16, 3), 256, 0, stream>>>(x, Wq, bq, Q, Wk, bk, Kc, Wv, bv, Vc);
    // top-k + attention (also performs the pairwise_g passthrough copy)
    attn_topk<<<dim3(NN, BS), 256, 0, stream>>>(pg, mask, lW1, lb1, lW2, lb2, lW3, lb3,
                                                Q, Kc, Vc, O, out);
    // output projection
    gemm3<<<dim3(BS*NN/16, 1), 256, 0, stream>>>(O, Wo, bo, out + OUT_OFF,
                                                 Wo, bo, out + OUT_OFF,
                                                 Wo, bo, out + OUT_OFF);
    // mask passthrough (as 0.0/1.0 floats)
    write_mask<<<dim3(16), 256, 0, stream>>>(mask, out + MASK_OFF);
}